// Round 17
// baseline (357.961 us; speedup 1.0000x reference)
//
#include <hip/hip_runtime.h>
#include <hip/hip_bf16.h>
#include <cstdint>
#include <cstddef>

#define S 4096
#define D 1024
#define H 16
#define HD 64
#define BATCH 2
#define M_TOK 8192   // BATCH*S
#define K2 2048

typedef short short8 __attribute__((ext_vector_type(8)));
typedef __bf16 bf16x8 __attribute__((ext_vector_type(8)));
typedef float f32x4 __attribute__((ext_vector_type(4)));
typedef float f32x16 __attribute__((ext_vector_type(16)));
typedef unsigned int u32;

static __device__ __forceinline__ ushort f2bf(float f) {
  union { float f; uint32_t u; } v; v.f = f;
  uint32_t u = v.u + 0x7FFFu + ((v.u >> 16) & 1u);
  return (ushort)(u >> 16);
}
static __device__ __forceinline__ float bf2f(ushort h) {
  union { uint32_t u; float f; } v; v.u = ((uint32_t)h) << 16; return v.f;
}
static __device__ __forceinline__ uint32_t cvtpk(float lo, float hi) {
  uint32_t r;
  asm("v_cvt_pk_bf16_f32 %0, %1, %2" : "=v"(r) : "v"(lo), "v"(hi));
  return r;
}
static __device__ __forceinline__ float vexp2(float x) {
  float r;
  asm("v_exp_f32 %0, %1" : "=v"(r) : "v"(x));
  return r;
}
static __device__ __forceinline__ bf16x8 pack4(uint32_t a, uint32_t b, uint32_t c, uint32_t d) {
  union { uint32_t u[4]; bf16x8 v; } z;
  z.u[0] = a; z.u[1] = b; z.u[2] = c; z.u[3] = d;
  return z.v;
}
// async global->LDS, 16B per lane; LDS dest = wave-uniform base + lane*16
static __device__ __forceinline__ void gld16(const void* g, void* l) {
  __builtin_amdgcn_global_load_lds(
      (const __attribute__((address_space(1))) u32*)g,
      (__attribute__((address_space(3))) u32*)l, 16, 0, 0);
}
static __device__ __forceinline__ ushort sgn(float a) {
  return a > 0.f ? 0x3F80 : (a < 0.f ? 0xBF80 : 0);
}

// ---------------- prep: x -> [hi|lo] bf16 concat (vectorized) ----------------
__global__ void prep_x(const float* __restrict__ x, ushort* __restrict__ xcat) {
  int i = blockIdx.x * blockDim.x + threadIdx.x;
  const int total = M_TOK * 128;   // groups of 8 floats
  for (; i < total; i += gridDim.x * blockDim.x) {
    int row = i >> 7, c8 = (i & 127) * 8;
    const float* px = &x[(size_t)row * 1024 + c8];
    float4 a = *(const float4*)px;
    float4 b = *(const float4*)(px + 4);
    float va[8] = {a.x, a.y, a.z, a.w, b.x, b.y, b.z, b.w};
    union { ushort u[8]; short8 v; } Hh, Ll;
#pragma unroll
    for (int j = 0; j < 8; ++j) {
      ushort h = f2bf(va[j]);
      Hh.u[j] = h;
      Ll.u[j] = f2bf(va[j] - bf2f(h));
    }
    *(short8*)&xcat[(size_t)row * K2 + c8] = Hh.v;
    *(short8*)&xcat[(size_t)row * K2 + 1024 + c8] = Ll.v;
  }
}

// W -> sign(W) bf16; Wq/Wk/Wv concat rows [3072][1024]; Wo separate
__global__ void prep_w(const float* __restrict__ wq, const float* __restrict__ wk,
                       const float* __restrict__ wv, const float* __restrict__ wo,
                       ushort* __restrict__ wcat, ushort* __restrict__ wob) {
  int i = blockIdx.x * blockDim.x + threadIdx.x;
  const int total = (D * D) / 4;
  for (; i < total; i += gridDim.x * blockDim.x) {
    float4 a;
    union { ushort u[4]; uint2 v; } t;
    a = *(const float4*)&wq[i * 4];
    t.u[0] = sgn(a.x); t.u[1] = sgn(a.y); t.u[2] = sgn(a.z); t.u[3] = sgn(a.w);
    *(uint2*)&wcat[i * 4] = t.v;
    a = *(const float4*)&wk[i * 4];
    t.u[0] = sgn(a.x); t.u[1] = sgn(a.y); t.u[2] = sgn(a.z); t.u[3] = sgn(a.w);
    *(uint2*)&wcat[D * D + i * 4] = t.v;
    a = *(const float4*)&wv[i * 4];
    t.u[0] = sgn(a.x); t.u[1] = sgn(a.y); t.u[2] = sgn(a.z); t.u[3] = sgn(a.w);
    *(uint2*)&wcat[2 * D * D + i * 4] = t.v;
    a = *(const float4*)&wo[i * 4];
    t.u[0] = sgn(a.x); t.u[1] = sgn(a.y); t.u[2] = sgn(a.z); t.u[3] = sgn(a.w);
    *(uint2*)&wob[i * 4] = t.v;
  }
}

// ---------------- gemm256: 256x256 tile, BK=32, 3-buffer counted-vmcnt pipeline (T3+T4) ----------------
// Grid (32, 12): bn<8 -> Q/K (K=2048 over hi|lo, hi-lo epilogue); bn>=8 -> V (K=1024 hi-only,
// plain V^T epilogue). Bw row indexing (bn*256+row)*1024 lands on Wq/Wk/Wv rows directly.
__global__ __launch_bounds__(512, 2) void gemm256(
    const ushort* __restrict__ A, const ushort* __restrict__ Bw,
    ushort* __restrict__ q_hi, ushort* __restrict__ q_lo,
    ushort* __restrict__ k_hi, ushort* __restrict__ k_lo,
    ushort* __restrict__ v_t)
{
  __shared__ ushort smA[3][256 * 32];
  __shared__ ushort smB[3][256 * 32];
  const int tid = threadIdx.x;
  const int l = tid & 63;
  const int w = tid >> 6;          // 0..7
  const int x = l & 15, g = l >> 4;
  const int wm = w >> 2, wn = w & 3;
  const int bm = blockIdx.x, bn = blockIdx.y;
  const int NS = (bn < 8) ? 64 : 32;   // K-steps (V uses hi half only)

  const ushort* gA[2]; const ushort* gB[2]; int ldso[2];
#pragma unroll
  for (int r = 0; r < 2; ++r) {
    int q = r * 512 + tid;
    int row = q >> 2;
    int blk = (q & 3) ^ ((row & 3) ^ ((row >> 2) & 3));
    gA[r] = &A[(size_t)(bm * 256 + row) * 2048 + blk * 8];
    gB[r] = &Bw[(size_t)(bn * 256 + row) * 1024 + blk * 8];
    ldso[r] = (r * 512 + w * 64) * 8;
  }

  f32x4 acc[8][4] = {};

  // prologue: stage K-tiles 0,1 into bufs 0,1
#pragma unroll
  for (int r = 0; r < 2; ++r) {
    gld16(gA[r] + 0, &smA[0][ldso[r]]);
    gld16(gB[r] + 0, &smB[0][ldso[r]]);
  }
#pragma unroll
  for (int r = 0; r < 2; ++r) {
    gld16(gA[r] + 32, &smA[1][ldso[r]]);
    gld16(gB[r] + ((32) & 1023), &smB[1][ldso[r]]);
  }

  const int swz = (x & 3) ^ ((x >> 2) & 3);
  int cb = 0;
  for (int s = 0; s < NS; ++s) {
    if (s < NS - 1) {
      asm volatile("s_waitcnt vmcnt(4)" ::: "memory");
    } else {
      asm volatile("s_waitcnt vmcnt(0)" ::: "memory");
    }
    __builtin_amdgcn_s_barrier();

    if (s + 2 < NS) {
      int nb = cb - 1; if (nb < 0) nb = 2;
      int k0 = (s + 2) * 32;
#pragma unroll
      for (int r = 0; r < 2; ++r) {
        gld16(gA[r] + k0, &smA[nb][ldso[r]]);
        gld16(gB[r] + (k0 & 1023), &smB[nb][ldso[r]]);
      }
    }

    const ushort* bA = smA[cb];
    const ushort* bB = smB[cb];
    bf16x8 af[8], bf_[4];
#pragma unroll
    for (int m = 0; m < 8; ++m)
      af[m] = *(const bf16x8*)&bA[(wm * 128 + m * 16 + x) * 32 + (g ^ swz) * 8];
#pragma unroll
    for (int n = 0; n < 4; ++n)
      bf_[n] = *(const bf16x8*)&bB[(wn * 64 + n * 16 + x) * 32 + (g ^ swz) * 8];

    __builtin_amdgcn_s_setprio(1);
#pragma unroll
    for (int m = 0; m < 8; ++m)
#pragma unroll
      for (int n = 0; n < 4; ++n)
        acc[m][n] = __builtin_amdgcn_mfma_f32_16x16x32_bf16(af[m], bf_[n], acc[m][n], 0, 0, 0);
    __builtin_amdgcn_s_setprio(0);

    cb = (cb == 2) ? 0 : cb + 1;
  }

#pragma unroll
  for (int m = 0; m < 8; ++m)
#pragma unroll
    for (int n = 0; n < 4; ++n)
#pragma unroll
      for (int r = 0; r < 4; ++r) {
        int rowg = bm * 256 + wm * 128 + m * 16 + g * 4 + r;
        int colg = bn * 256 + wn * 64 + n * 16 + x;
        float v = acc[m][n][r];
        int bi = rowg >> 12, ntok = rowg & 4095;
        int cg = colg & 1023;
        int h = cg >> 6, hd = cg & 63;
        size_t bhb = (size_t)(bi * H + h) * (S * HD);
        if (bn < 8) {
          int proj = colg >> 10;
          ushort* oh = (proj == 0) ? q_hi : k_hi;
          ushort* ol = (proj == 0) ? q_lo : k_lo;
          size_t off = bhb + (size_t)ntok * HD + hd;
          ushort hiv = f2bf(v);
          oh[off] = hiv;
          ol[off] = f2bf(v - bf2f(hiv));
        } else {
          // plain V^T (32x32 PV A-frag reads contiguous tokens)
          v_t[bhb + (size_t)hd * S + ntok] = f2bf(v);
        }
      }
}

// ---------------- GEMM (m97): EPI 2: fp32 + bias (out-projection) ----------------
template<int KK, int BROW, int AST>
__global__ __launch_bounds__(256) void gemm97o(
    const ushort* __restrict__ A, const ushort* __restrict__ Bw,
    float* __restrict__ of, const float* __restrict__ bias)
{
  __shared__ ushort smA[128 * 32];
  __shared__ ushort smB[128 * 32];
  const int tid = threadIdx.x;
  const int l = tid & 63;
  const int w = tid >> 6;
  const int x = l & 15, g = l >> 4;
  const int wm = w >> 1, wn = w & 1;
  const int bm = blockIdx.x, bn = blockIdx.y;

  const ushort* gA[2]; const ushort* gB[2]; int ldso[2];
#pragma unroll
  for (int p = 0; p < 2; ++p) {
    int q = p * 256 + tid;
    gA[p] = &A[(size_t)(bm * 128 + (q >> 2)) * AST + (q & 3) * 8];
    gB[p] = &Bw[(size_t)(bn * 128 + (q >> 2)) * BROW + (q & 3) * 8];
    ldso[p] = (p * 256 + w * 64) * 8;
  }

  f32x4 acc[4][4] = {};

  for (int k0 = 0; k0 < KK; k0 += 32) {
    __syncthreads();
#pragma unroll
    for (int p = 0; p < 2; ++p) {
      gld16(gA[p] + k0, &smA[ldso[p]]);
      gld16(gB[p] + (k0 & (BROW - 1)), &smB[ldso[p]]);
    }
    __syncthreads();
    bf16x8 af[4], bf_[4];
#pragma unroll
    for (int m = 0; m < 4; ++m)
      af[m] = *(const bf16x8*)&smA[(wm * 64 + m * 16 + x) * 32 + g * 8];
#pragma unroll
    for (int n = 0; n < 4; ++n)
      bf_[n] = *(const bf16x8*)&smB[(wn * 64 + n * 16 + x) * 32 + g * 8];
#pragma unroll
    for (int m = 0; m < 4; ++m)
#pragma unroll
      for (int n = 0; n < 4; ++n)
        acc[m][n] = __builtin_amdgcn_mfma_f32_16x16x32_bf16(af[m], bf_[n], acc[m][n], 0, 0, 0);
  }

#pragma unroll
  for (int m = 0; m < 4; ++m)
#pragma unroll
    for (int n = 0; n < 4; ++n)
#pragma unroll
      for (int r = 0; r < 4; ++r) {
        int rowg = bm * 128 + wm * 64 + m * 16 + g * 4 + r;
        int colg = bn * 128 + wn * 64 + n * 16 + x;
        of[(size_t)rowg * D + colg] = acc[m][n][r] + bias[colg];
      }
}

// ---------------- flash16: 32x32x16 MFMA (best flash: 195us), T12 permlane P-pack ----------------
__global__ __launch_bounds__(256) void flash16(
    const ushort* __restrict__ qhi, const ushort* __restrict__ qlo,
    const ushort* __restrict__ khi, const ushort* __restrict__ klo,
    const ushort* __restrict__ vt, ushort* __restrict__ ctx)
{
  __shared__ ushort smKhi[2][64 * 64];
  __shared__ ushort smKlo[2][64 * 64];
  __shared__ ushort smVT[2][64 * 64];

  const int tid = threadIdx.x;
  const int l = tid & 63;
  const int w = tid >> 6;
  const int q31 = l & 31;
  const int g2 = l >> 5;        // 0..1
  const int l7 = l & 7;
  const int bh = blockIdx.x;
  const int qt = (int)(gridDim.y - 1) - (int)blockIdx.y;   // heavy tiles first
  const int qbase = qt * 128;
  const size_t qkbase = (size_t)bh * S * HD;

  int soff_k[2]; size_t soff_v[2]; int ldso[2];
#pragma unroll
  for (int p = 0; p < 2; ++p) {
    int q = p * 256 + tid;
    int r2 = q >> 3;
    int sb = (q & 7) ^ (r2 & 7);
    soff_k[p] = r2 * HD + sb * 8;
    soff_v[p] = (size_t)r2 * S + sb * 8;
    ldso[p] = (p * 256 + w * 64) * 8;
  }
  const ushort* khb = khi + qkbase;
  const ushort* klb = klo + qkbase;
  const ushort* vtb = vt + qkbase;

  // Q fragments (B-operand of 32x32x16): [hi/lo][s2]; lane: q=q31, d = 16*s2 + 8*g2 + j
  bf16x8 bq[2][4];
  {
    int qrow = qbase + w * 32 + q31;
    size_t base = qkbase + (size_t)qrow * HD + g2 * 8;
#pragma unroll
    for (int s2 = 0; s2 < 4; ++s2) {
      bq[0][s2] = *(const bf16x8*)&qhi[base + s2 * 16];
      bq[1][s2] = *(const bf16x8*)&qlo[base + s2 * 16];
    }
  }

  float mrun = -1e30f;
  float lrun = 0.f;            // lane-partial; reduced at epilogue
  f32x16 oacc0 = {}, oacc1 = {};

  const int kvmax = (qbase + 127) >> 6;
  const int qmaxw = qbase + w * 32 + 31;
  const float C1 = 0.125f * 1.44269504f;
  const float TH = 8.0f / C1;

#pragma unroll
  for (int p = 0; p < 2; ++p) {
    gld16(khb + soff_k[p], &smKhi[0][ldso[p]]);
    gld16(klb + soff_k[p], &smKlo[0][ldso[p]]);
    gld16(vtb + soff_v[p], &smVT[0][ldso[p]]);
  }
  __syncthreads();

  int cur = 0;
  for (int kv = 0; kv <= kvmax; ++kv) {
    if (kv < kvmax) {
      const ushort* kh = khb + (size_t)(kv + 1) * (64 * HD);
      const ushort* kl = klb + (size_t)(kv + 1) * (64 * HD);
      const ushort* vp = vtb + (size_t)(kv + 1) * 64;
      int nb = cur ^ 1;
#pragma unroll
      for (int p = 0; p < 2; ++p) {
        gld16(kh + soff_k[p], &smKhi[nb][ldso[p]]);
        gld16(kl + soff_k[p], &smKlo[nb][ldso[p]]);
        gld16(vp + soff_v[p], &smVT[nb][ldso[p]]);
      }
    }

    if (kv * 64 <= qmaxw) {
      const ushort* bKhi = smKhi[cur];
      const ushort* bKlo = smKlo[cur];
      const ushort* bVT = smVT[cur];

      // ---- QK^T swapped, 32x32x16: sc[T] covers k-tokens [32T, 32T+32) x 32 q ----
      f32x16 sc0 = {}, sc1 = {};
      __builtin_amdgcn_s_setprio(1);
#pragma unroll
      for (int s2 = 0; s2 < 4; ++s2) {
        {
          int pb = q31 * 64 + (((2 * s2 + g2)) ^ l7) * 8;
          bf16x8 kH = *(const bf16x8*)&bKhi[pb];
          bf16x8 kL = *(const bf16x8*)&bKlo[pb];
          sc0 = __builtin_amdgcn_mfma_f32_32x32x16_bf16(kH, bq[0][s2], sc0, 0, 0, 0);
          sc0 = __builtin_amdgcn_mfma_f32_32x32x16_bf16(kL, bq[0][s2], sc0, 0, 0, 0);
          sc0 = __builtin_amdgcn_mfma_f32_32x32x16_bf16(kH, bq[1][s2], sc0, 0, 0, 0);
        }
        {
          int pb = (32 + q31) * 64 + (((2 * s2 + g2)) ^ l7) * 8;
          bf16x8 kH = *(const bf16x8*)&bKhi[pb];
          bf16x8 kL = *(const bf16x8*)&bKlo[pb];
          sc1 = __builtin_amdgcn_mfma_f32_32x32x16_bf16(kH, bq[0][s2], sc1, 0, 0, 0);
          sc1 = __builtin_amdgcn_mfma_f32_32x32x16_bf16(kL, bq[0][s2], sc1, 0, 0, 0);
          sc1 = __builtin_amdgcn_mfma_f32_32x32x16_bf16(kH, bq[1][s2], sc1, 0, 0, 0);
        }
      }
      __builtin_amdgcn_s_setprio(0);

      // ---- mask (diagonal tiles only) ----
      if (kv * 64 + 63 > qbase + w * 32) {
        int qglob = qbase + w * 32 + q31;
        int kb = kv * 64 + 4 * g2;
#pragma unroll
        for (int r = 0; r < 16; ++r) {
          int k5 = (r & 3) + 8 * (r >> 2);
          if (kb + k5 > qglob) sc0[r] = -1e30f;
          if (kb + 32 + k5 > qglob) sc1[r] = -1e30f;
        }
      }

      // ---- softmax (lane-local 32) ----
      float mt[8];
#pragma unroll
      for (int r = 0; r < 8; ++r)
        mt[r] = fmaxf(fmaxf(sc0[2 * r], sc0[2 * r + 1]), fmaxf(sc1[2 * r], sc1[2 * r + 1]));
      float mloc = fmaxf(fmaxf(fmaxf(mt[0], mt[1]), fmaxf(mt[2], mt[3])),
                         fmaxf(fmaxf(mt[4], mt[5]), fmaxf(mt[6], mt[7])));
      if (__any(mloc > mrun + TH)) {
        float mx = fmaxf(mloc, __shfl_xor(mloc, 32));
        float mnew = fmaxf(mrun, mx);
        float scal = vexp2((mrun - mnew) * C1);
        mrun = mnew;
        lrun *= scal;
        oacc0 *= scal;
        oacc1 *= scal;
      }
      float mc = mrun * C1;
#pragma unroll
      for (int r = 0; r < 16; ++r) {
        sc0[r] = vexp2(sc0[r] * C1 - mc);
        sc1[r] = vexp2(sc1[r] * C1 - mc);
      }
      float st[8];
#pragma unroll
      for (int r = 0; r < 8; ++r)
        st[r] = (sc0[2 * r] + sc0[2 * r + 1]) + (sc1[2 * r] + sc1[2 * r + 1]);
      lrun += ((st[0] + st[1]) + (st[2] + st[3])) + ((st[4] + st[5]) + (st[6] + st[7]));

      // ---- P pack -> B-frags via permlane32_swap (T12) ----
      uint32_t pbw[4][4];
#pragma unroll
      for (int s2 = 0; s2 < 4; ++s2) {
        const int s1 = s2 & 1;
#pragma unroll
        for (int p = 0; p < 2; ++p) {
          uint32_t a, b;
          if (s2 < 2) {
            a = cvtpk(sc0[2 * p + 8 * s1], sc0[2 * p + 1 + 8 * s1]);
            b = cvtpk(sc0[2 * p + 4 + 8 * s1], sc0[2 * p + 5 + 8 * s1]);
          } else {
            a = cvtpk(sc1[2 * p + 8 * s1], sc1[2 * p + 1 + 8 * s1]);
            b = cvtpk(sc1[2 * p + 4 + 8 * s1], sc1[2 * p + 5 + 8 * s1]);
          }
          asm volatile("v_permlane32_swap_b32 %0, %1" : "+v"(a), "+v"(b));
          pbw[s2][p] = a;
          pbw[s2][2 + p] = b;
        }
      }

      // ---- PV: O^T += V^T * P, 32x32x16 ----
      __builtin_amdgcn_s_setprio(1);
#pragma unroll
      for (int s2 = 0; s2 < 4; ++s2) {
        bf16x8 bp = pack4(pbw[s2][0], pbw[s2][1], pbw[s2][2], pbw[s2][3]);
        {
          bf16x8 vf = *(const bf16x8*)&bVT[(q31)*64 + (((2 * s2 + g2)) ^ l7) * 8];
          oacc0 = __builtin_amdgcn_mfma_f32_32x32x16_bf16(vf, bp, oacc0, 0, 0, 0);
        }
        {
          bf16x8 vf = *(const bf16x8*)&bVT[(32 + q31) * 64 + (((2 * s2 + g2)) ^ l7) * 8];
          oacc1 = __builtin_amdgcn_mfma_f32_32x32x16_bf16(vf, bp, oacc1, 0, 0, 0);
        }
      }
      __builtin_amdgcn_s_setprio(0);
    }

    __syncthreads();
    cur ^= 1;
  }

  const int b = bh >> 4, h = bh & 15;
  {
    float ls = lrun + __shfl_xor(lrun, 32);
    float inv = 1.0f / ls;
    int tok = qbase + w * 32 + q31;
    size_t rbase = (size_t)(b * S + tok) * D + h * 64;
#pragma unroll
    for (int r2 = 0; r2 < 4; ++r2) {
      uint2 uu;
      uu.x = cvtpk(oacc0[4 * r2] * inv, oacc0[4 * r2 + 1] * inv);
      uu.y = cvtpk(oacc0[4 * r2 + 2] * inv, oacc0[4 * r2 + 3] * inv);
      *(uint2*)&ctx[rbase + 8 * r2 + 4 * g2] = uu;
      uu.x = cvtpk(oacc1[4 * r2] * inv, oacc1[4 * r2 + 1] * inv);
      uu.y = cvtpk(oacc1[4 * r2 + 2] * inv, oacc1[4 * r2 + 3] * inv);
      *(uint2*)&ctx[rbase + 32 + 8 * r2 + 4 * g2] = uu;
    }
  }
}

extern "C" void kernel_launch(void* const* d_in, const int* in_sizes, int n_in,
                              void* d_out, int out_size, void* d_ws, size_t ws_size,
                              hipStream_t stream) {
  const float* x  = (const float*)d_in[0];
  const float* Wq = (const float*)d_in[1];
  const float* Wk = (const float*)d_in[2];
  const float* Wv = (const float*)d_in[3];
  const float* Wo = (const float*)d_in[4];
  const float* bo = (const float*)d_in[5];
  float* out = (float*)d_out;

  if (ws_size < (size_t)120 * 1024 * 1024) return;

  char* ws = (char*)d_ws;
  const size_t MB = 1024 * 1024;
  ushort* xcat = (ushort*)(ws);              // 32MB; ctx aliases (xcat dead after projections)
  ushort* ctx  = (ushort*)(ws);
  ushort* wcat = (ushort*)(ws + 32 * MB);    // 6MB [3072][1024]
  ushort* wob  = (ushort*)(ws + 38 * MB);    // 2MB
  ushort* qhi  = (ushort*)(ws + 40 * MB);    // 16MB each
  ushort* qlo  = (ushort*)(ws + 56 * MB);
  ushort* khi  = (ushort*)(ws + 72 * MB);
  ushort* klo  = (ushort*)(ws + 88 * MB);
  ushort* vt   = (ushort*)(ws + 104 * MB);

  prep_x<<<2048, 256, 0, stream>>>(x, xcat);
  prep_w<<<1024, 256, 0, stream>>>(Wq, Wk, Wv, Wo, wcat, wob);

  // Q,K,V in ONE 256^2 counted-vmcnt pipeline (V blocks: bn 8-11, K=1024 hi-only).
  gemm256<<<dim3(32, 12), 512, 0, stream>>>(xcat, wcat, qhi, qlo, khi, klo, vt);

  flash16<<<dim3(BATCH * H, S / 128), 256, 0, stream>>>(qhi, qlo, khi, klo, vt, ctx);

  gemm97o<1024, 1024, 1024><<<dim3(64, 8), 256, 0, stream>>>(ctx, wob, out, bo);
}

// Round 18
// 327.930 us; speedup vs baseline: 1.0916x; 1.0916x over previous
//
#include <hip/hip_runtime.h>
#include <hip/hip_bf16.h>
#include <cstdint>
#include <cstddef>

#define S 4096
#define D 1024
#define H 16
#define HD 64
#define BATCH 2
#define M_TOK 8192   // BATCH*S
#define K2 2048

typedef short short8 __attribute__((ext_vector_type(8)));
typedef __bf16 bf16x8 __attribute__((ext_vector_type(8)));
typedef float f32x4 __attribute__((ext_vector_type(4)));
typedef float f32x16 __attribute__((ext_vector_type(16)));
typedef unsigned int u32;

static __device__ __forceinline__ ushort f2bf(float f) {
  union { float f; uint32_t u; } v; v.f = f;
  uint32_t u = v.u + 0x7FFFu + ((v.u >> 16) & 1u);
  return (ushort)(u >> 16);
}
static __device__ __forceinline__ float bf2f(ushort h) {
  union { uint32_t u; float f; } v; v.u = ((uint32_t)h) << 16; return v.f;
}
static __device__ __forceinline__ uint32_t cvtpk(float lo, float hi) {
  uint32_t r;
  asm("v_cvt_pk_bf16_f32 %0, %1, %2" : "=v"(r) : "v"(lo), "v"(hi));
  return r;
}
static __device__ __forceinline__ float vexp2(float x) {
  float r;
  asm("v_exp_f32 %0, %1" : "=v"(r) : "v"(x));
  return r;
}
static __device__ __forceinline__ bf16x8 pack4(uint32_t a, uint32_t b, uint32_t c, uint32_t d) {
  union { uint32_t u[4]; bf16x8 v; } z;
  z.u[0] = a; z.u[1] = b; z.u[2] = c; z.u[3] = d;
  return z.v;
}
// async global->LDS, 16B per lane; LDS dest = wave-uniform base + lane*16
static __device__ __forceinline__ void gld16(const void* g, void* l) {
  __builtin_amdgcn_global_load_lds(
      (const __attribute__((address_space(1))) u32*)g,
      (__attribute__((address_space(3))) u32*)l, 16, 0, 0);
}
static __device__ __forceinline__ ushort sgn(float a) {
  return a > 0.f ? 0x3F80 : (a < 0.f ? 0xBF80 : 0);
}

// ---------------- prep: x -> [hi|lo] bf16 concat (vectorized) ----------------
__global__ void prep_x(const float* __restrict__ x, ushort* __restrict__ xcat) {
  int i = blockIdx.x * blockDim.x + threadIdx.x;
  const int total = M_TOK * 128;   // groups of 8 floats
  for (; i < total; i += gridDim.x * blockDim.x) {
    int row = i >> 7, c8 = (i & 127) * 8;
    const float* px = &x[(size_t)row * 1024 + c8];
    float4 a = *(const float4*)px;
    float4 b = *(const float4*)(px + 4);
    float va[8] = {a.x, a.y, a.z, a.w, b.x, b.y, b.z, b.w};
    union { ushort u[8]; short8 v; } Hh, Ll;
#pragma unroll
    for (int j = 0; j < 8; ++j) {
      ushort h = f2bf(va[j]);
      Hh.u[j] = h;
      Ll.u[j] = f2bf(va[j] - bf2f(h));
    }
    *(short8*)&xcat[(size_t)row * K2 + c8] = Hh.v;
    *(short8*)&xcat[(size_t)row * K2 + 1024 + c8] = Ll.v;
  }
}

// W -> sign(W) bf16; Wq/Wk/Wv concat rows [3072][1024]; Wo separate
__global__ void prep_w(const float* __restrict__ wq, const float* __restrict__ wk,
                       const float* __restrict__ wv, const float* __restrict__ wo,
                       ushort* __restrict__ wcat, ushort* __restrict__ wob) {
  int i = blockIdx.x * blockDim.x + threadIdx.x;
  const int total = (D * D) / 4;
  for (; i < total; i += gridDim.x * blockDim.x) {
    float4 a;
    union { ushort u[4]; uint2 v; } t;
    a = *(const float4*)&wq[i * 4];
    t.u[0] = sgn(a.x); t.u[1] = sgn(a.y); t.u[2] = sgn(a.z); t.u[3] = sgn(a.w);
    *(uint2*)&wcat[i * 4] = t.v;
    a = *(const float4*)&wk[i * 4];
    t.u[0] = sgn(a.x); t.u[1] = sgn(a.y); t.u[2] = sgn(a.z); t.u[3] = sgn(a.w);
    *(uint2*)&wcat[D * D + i * 4] = t.v;
    a = *(const float4*)&wv[i * 4];
    t.u[0] = sgn(a.x); t.u[1] = sgn(a.y); t.u[2] = sgn(a.z); t.u[3] = sgn(a.w);
    *(uint2*)&wcat[2 * D * D + i * 4] = t.v;
    a = *(const float4*)&wo[i * 4];
    t.u[0] = sgn(a.x); t.u[1] = sgn(a.y); t.u[2] = sgn(a.z); t.u[3] = sgn(a.w);
    *(uint2*)&wob[i * 4] = t.v;
  }
}

// ---------------- gemm256: 256x256 tile, BK=32, 3-buffer counted-vmcnt pipeline (T3+T4) ----------------
// Q/K only (grid 32x8): K=2048 over hi|lo (B rows wrap at 1024), hi-lo epilogue.
__global__ __launch_bounds__(512, 2) void gemm256(
    const ushort* __restrict__ A, const ushort* __restrict__ Bw,
    ushort* __restrict__ q_hi, ushort* __restrict__ q_lo,
    ushort* __restrict__ k_hi, ushort* __restrict__ k_lo)
{
  __shared__ ushort smA[3][256 * 32];
  __shared__ ushort smB[3][256 * 32];
  const int tid = threadIdx.x;
  const int l = tid & 63;
  const int w = tid >> 6;          // 0..7
  const int x = l & 15, g = l >> 4;
  const int wm = w >> 2, wn = w & 3;
  const int bm = blockIdx.x, bn = blockIdx.y;

  const ushort* gA[2]; const ushort* gB[2]; int ldso[2];
#pragma unroll
  for (int r = 0; r < 2; ++r) {
    int q = r * 512 + tid;
    int row = q >> 2;
    int blk = (q & 3) ^ ((row & 3) ^ ((row >> 2) & 3));
    gA[r] = &A[(size_t)(bm * 256 + row) * 2048 + blk * 8];
    gB[r] = &Bw[(size_t)(bn * 256 + row) * 1024 + blk * 8];
    ldso[r] = (r * 512 + w * 64) * 8;
  }

  f32x4 acc[8][4] = {};

#pragma unroll
  for (int r = 0; r < 2; ++r) {
    gld16(gA[r] + 0, &smA[0][ldso[r]]);
    gld16(gB[r] + 0, &smB[0][ldso[r]]);
  }
#pragma unroll
  for (int r = 0; r < 2; ++r) {
    gld16(gA[r] + 32, &smA[1][ldso[r]]);
    gld16(gB[r] + ((32) & 1023), &smB[1][ldso[r]]);
  }

  const int swz = (x & 3) ^ ((x >> 2) & 3);
  int cb = 0;
  for (int s = 0; s < 64; ++s) {
    if (s < 63) {
      asm volatile("s_waitcnt vmcnt(4)" ::: "memory");
    } else {
      asm volatile("s_waitcnt vmcnt(0)" ::: "memory");
    }
    __builtin_amdgcn_s_barrier();

    if (s + 2 < 64) {
      int nb = cb - 1; if (nb < 0) nb = 2;
      int k0 = (s + 2) * 32;
#pragma unroll
      for (int r = 0; r < 2; ++r) {
        gld16(gA[r] + k0, &smA[nb][ldso[r]]);
        gld16(gB[r] + (k0 & 1023), &smB[nb][ldso[r]]);
      }
    }

    const ushort* bA = smA[cb];
    const ushort* bB = smB[cb];
    bf16x8 af[8], bf_[4];
#pragma unroll
    for (int m = 0; m < 8; ++m)
      af[m] = *(const bf16x8*)&bA[(wm * 128 + m * 16 + x) * 32 + (g ^ swz) * 8];
#pragma unroll
    for (int n = 0; n < 4; ++n)
      bf_[n] = *(const bf16x8*)&bB[(wn * 64 + n * 16 + x) * 32 + (g ^ swz) * 8];

    __builtin_amdgcn_s_setprio(1);
#pragma unroll
    for (int m = 0; m < 8; ++m)
#pragma unroll
      for (int n = 0; n < 4; ++n)
        acc[m][n] = __builtin_amdgcn_mfma_f32_16x16x32_bf16(af[m], bf_[n], acc[m][n], 0, 0, 0);
    __builtin_amdgcn_s_setprio(0);

    cb = (cb == 2) ? 0 : cb + 1;
  }

#pragma unroll
  for (int m = 0; m < 8; ++m)
#pragma unroll
    for (int n = 0; n < 4; ++n)
#pragma unroll
      for (int r = 0; r < 4; ++r) {
        int rowg = bm * 256 + wm * 128 + m * 16 + g * 4 + r;
        int colg = bn * 256 + wn * 64 + n * 16 + x;
        float v = acc[m][n][r];
        int bi = rowg >> 12, ntok = rowg & 4095;
        int proj = colg >> 10;
        int cg = colg & 1023;
        int h = cg >> 6, hd = cg & 63;
        ushort* oh = (proj == 0) ? q_hi : k_hi;
        ushort* ol = (proj == 0) ? q_lo : k_lo;
        size_t off = (size_t)(bi * H + h) * (S * HD) + (size_t)ntok * HD + hd;
        ushort hiv = f2bf(v);
        oh[off] = hiv;
        ol[off] = f2bf(v - bf2f(hiv));
      }
}

// ---------------- gemm128p: 128x128 tile, 3-buffer counted-vmcnt pipeline (T3+T4 at 128 scale) ----------------
// EPI 1: plain V^T transpose epilogue. EPI 2: fp32 + bias.
template<int EPI, int KK, int BROW, int AST>
__global__ __launch_bounds__(256) void gemm128p(
    const ushort* __restrict__ A, const ushort* __restrict__ Bw,
    ushort* __restrict__ v_t,
    float* __restrict__ of, const float* __restrict__ bias)
{
  __shared__ ushort smA[3][128 * 32];
  __shared__ ushort smB[3][128 * 32];
  const int tid = threadIdx.x;
  const int l = tid & 63;
  const int w = tid >> 6;          // 0..3
  const int x = l & 15, g = l >> 4;
  const int wm = w >> 1, wn = w & 1;
  const int bm = blockIdx.x, bn = blockIdx.y;
  const int NS = KK / 32;

  // staging: pass r chunk q=r*256+tid -> (row=q>>2, blk=(q&3)^swz(row)); reader un-swizzles.
  const ushort* gA[2]; const ushort* gB[2]; int ldso[2];
#pragma unroll
  for (int r = 0; r < 2; ++r) {
    int q = r * 256 + tid;
    int row = q >> 2;
    int blk = (q & 3) ^ ((row & 3) ^ ((row >> 2) & 3));
    gA[r] = &A[(size_t)(bm * 128 + row) * AST + blk * 8];
    gB[r] = &Bw[(size_t)(bn * 128 + row) * BROW + blk * 8];
    ldso[r] = (r * 256 + w * 64) * 8;
  }

  f32x4 acc[4][4] = {};

  // prologue: stage K-tiles 0,1 into bufs 0,1
#pragma unroll
  for (int r = 0; r < 2; ++r) {
    gld16(gA[r] + 0, &smA[0][ldso[r]]);
    gld16(gB[r] + 0, &smB[0][ldso[r]]);
  }
#pragma unroll
  for (int r = 0; r < 2; ++r) {
    gld16(gA[r] + 32, &smA[1][ldso[r]]);
    gld16(gB[r] + ((32) & (BROW - 1)), &smB[1][ldso[r]]);
  }

  const int swz = (x & 3) ^ ((x >> 2) & 3);
  int cb = 0;
  for (int s = 0; s < NS; ++s) {
    if (s < NS - 1) {
      asm volatile("s_waitcnt vmcnt(4)" ::: "memory");
    } else {
      asm volatile("s_waitcnt vmcnt(0)" ::: "memory");
    }
    __builtin_amdgcn_s_barrier();   // tile s ready; tile (s-1) fully consumed

    if (s + 2 < NS) {
      int nb = cb - 1; if (nb < 0) nb = 2;   // (cb+2)%3
      int k0 = (s + 2) * 32;
#pragma unroll
      for (int r = 0; r < 2; ++r) {
        gld16(gA[r] + k0, &smA[nb][ldso[r]]);
        gld16(gB[r] + (k0 & (BROW - 1)), &smB[nb][ldso[r]]);
      }
    }

    const ushort* bA = smA[cb];
    const ushort* bB = smB[cb];
    bf16x8 af[4], bf_[4];
#pragma unroll
    for (int m = 0; m < 4; ++m)
      af[m] = *(const bf16x8*)&bA[(wm * 64 + m * 16 + x) * 32 + (g ^ swz) * 8];
#pragma unroll
    for (int n = 0; n < 4; ++n)
      bf_[n] = *(const bf16x8*)&bB[(wn * 64 + n * 16 + x) * 32 + (g ^ swz) * 8];

    __builtin_amdgcn_s_setprio(1);
#pragma unroll
    for (int m = 0; m < 4; ++m)
#pragma unroll
      for (int n = 0; n < 4; ++n)
        acc[m][n] = __builtin_amdgcn_mfma_f32_16x16x32_bf16(af[m], bf_[n], acc[m][n], 0, 0, 0);
    __builtin_amdgcn_s_setprio(0);

    cb = (cb == 2) ? 0 : cb + 1;
  }

#pragma unroll
  for (int m = 0; m < 4; ++m)
#pragma unroll
    for (int n = 0; n < 4; ++n)
#pragma unroll
      for (int r = 0; r < 4; ++r) {
        int rowg = bm * 128 + wm * 64 + m * 16 + g * 4 + r;
        int colg = bn * 128 + wn * 64 + n * 16 + x;
        float v = acc[m][n][r];
        if (EPI == 2) {
          of[(size_t)rowg * D + colg] = v + bias[colg];
        } else {
          int bi = rowg >> 12, ntok = rowg & 4095;
          int cg = colg & 1023;
          int h = cg >> 6, hd = cg & 63;
          size_t bhb = (size_t)(bi * H + h) * (S * HD);
          v_t[bhb + (size_t)hd * S + ntok] = f2bf(v);   // plain V^T
        }
      }
}

// ---------------- flash16: 32x32x16 MFMA (best flash: 195us), T12 permlane P-pack ----------------
__global__ __launch_bounds__(256) void flash16(
    const ushort* __restrict__ qhi, const ushort* __restrict__ qlo,
    const ushort* __restrict__ khi, const ushort* __restrict__ klo,
    const ushort* __restrict__ vt, ushort* __restrict__ ctx)
{
  __shared__ ushort smKhi[2][64 * 64];
  __shared__ ushort smKlo[2][64 * 64];
  __shared__ ushort smVT[2][64 * 64];

  const int tid = threadIdx.x;
  const int l = tid & 63;
  const int w = tid >> 6;
  const int q31 = l & 31;
  const int g2 = l >> 5;        // 0..1
  const int l7 = l & 7;
  const int bh = blockIdx.x;
  const int qt = (int)(gridDim.y - 1) - (int)blockIdx.y;   // heavy tiles first
  const int qbase = qt * 128;
  const size_t qkbase = (size_t)bh * S * HD;

  int soff_k[2]; size_t soff_v[2]; int ldso[2];
#pragma unroll
  for (int p = 0; p < 2; ++p) {
    int q = p * 256 + tid;
    int r2 = q >> 3;
    int sb = (q & 7) ^ (r2 & 7);
    soff_k[p] = r2 * HD + sb * 8;
    soff_v[p] = (size_t)r2 * S + sb * 8;
    ldso[p] = (p * 256 + w * 64) * 8;
  }
  const ushort* khb = khi + qkbase;
  const ushort* klb = klo + qkbase;
  const ushort* vtb = vt + qkbase;

  // Q fragments (B-operand of 32x32x16): [hi/lo][s2]; lane: q=q31, d = 16*s2 + 8*g2 + j
  bf16x8 bq[2][4];
  {
    int qrow = qbase + w * 32 + q31;
    size_t base = qkbase + (size_t)qrow * HD + g2 * 8;
#pragma unroll
    for (int s2 = 0; s2 < 4; ++s2) {
      bq[0][s2] = *(const bf16x8*)&qhi[base + s2 * 16];
      bq[1][s2] = *(const bf16x8*)&qlo[base + s2 * 16];
    }
  }

  float mrun = -1e30f;
  float lrun = 0.f;            // lane-partial; reduced at epilogue
  f32x16 oacc0 = {}, oacc1 = {};

  const int kvmax = (qbase + 127) >> 6;
  const int qmaxw = qbase + w * 32 + 31;
  const float C1 = 0.125f * 1.44269504f;
  const float TH = 8.0f / C1;

#pragma unroll
  for (int p = 0; p < 2; ++p) {
    gld16(khb + soff_k[p], &smKhi[0][ldso[p]]);
    gld16(klb + soff_k[p], &smKlo[0][ldso[p]]);
    gld16(vtb + soff_v[p], &smVT[0][ldso[p]]);
  }
  __syncthreads();

  int cur = 0;
  for (int kv = 0; kv <= kvmax; ++kv) {
    if (kv < kvmax) {
      const ushort* kh = khb + (size_t)(kv + 1) * (64 * HD);
      const ushort* kl = klb + (size_t)(kv + 1) * (64 * HD);
      const ushort* vp = vtb + (size_t)(kv + 1) * 64;
      int nb = cur ^ 1;
#pragma unroll
      for (int p = 0; p < 2; ++p) {
        gld16(kh + soff_k[p], &smKhi[nb][ldso[p]]);
        gld16(kl + soff_k[p], &smKlo[nb][ldso[p]]);
        gld16(vp + soff_v[p], &smVT[nb][ldso[p]]);
      }
    }

    if (kv * 64 <= qmaxw) {
      const ushort* bKhi = smKhi[cur];
      const ushort* bKlo = smKlo[cur];
      const ushort* bVT = smVT[cur];

      // ---- QK^T swapped, 32x32x16: sc[T] covers k-tokens [32T, 32T+32) x 32 q ----
      f32x16 sc0 = {}, sc1 = {};
      __builtin_amdgcn_s_setprio(1);
#pragma unroll
      for (int s2 = 0; s2 < 4; ++s2) {
        {
          int pb = q31 * 64 + (((2 * s2 + g2)) ^ l7) * 8;
          bf16x8 kH = *(const bf16x8*)&bKhi[pb];
          bf16x8 kL = *(const bf16x8*)&bKlo[pb];
          sc0 = __builtin_amdgcn_mfma_f32_32x32x16_bf16(kH, bq[0][s2], sc0, 0, 0, 0);
          sc0 = __builtin_amdgcn_mfma_f32_32x32x16_bf16(kL, bq[0][s2], sc0, 0, 0, 0);
          sc0 = __builtin_amdgcn_mfma_f32_32x32x16_bf16(kH, bq[1][s2], sc0, 0, 0, 0);
        }
        {
          int pb = (32 + q31) * 64 + (((2 * s2 + g2)) ^ l7) * 8;
          bf16x8 kH = *(const bf16x8*)&bKhi[pb];
          bf16x8 kL = *(const bf16x8*)&bKlo[pb];
          sc1 = __builtin_amdgcn_mfma_f32_32x32x16_bf16(kH, bq[0][s2], sc1, 0, 0, 0);
          sc1 = __builtin_amdgcn_mfma_f32_32x32x16_bf16(kL, bq[0][s2], sc1, 0, 0, 0);
          sc1 = __builtin_amdgcn_mfma_f32_32x32x16_bf16(kH, bq[1][s2], sc1, 0, 0, 0);
        }
      }
      __builtin_amdgcn_s_setprio(0);

      // ---- mask (diagonal tiles only) ----
      if (kv * 64 + 63 > qbase + w * 32) {
        int qglob = qbase + w * 32 + q31;
        int kb = kv * 64 + 4 * g2;
#pragma unroll
        for (int r = 0; r < 16; ++r) {
          int k5 = (r & 3) + 8 * (r >> 2);
          if (kb + k5 > qglob) sc0[r] = -1e30f;
          if (kb + 32 + k5 > qglob) sc1[r] = -1e30f;
        }
      }

      // ---- softmax (lane-local 32) ----
      float mt[8];
#pragma unroll
      for (int r = 0; r < 8; ++r)
        mt[r] = fmaxf(fmaxf(sc0[2 * r], sc0[2 * r + 1]), fmaxf(sc1[2 * r], sc1[2 * r + 1]));
      float mloc = fmaxf(fmaxf(fmaxf(mt[0], mt[1]), fmaxf(mt[2], mt[3])),
                         fmaxf(fmaxf(mt[4], mt[5]), fmaxf(mt[6], mt[7])));
      if (__any(mloc > mrun + TH)) {
        float mx = fmaxf(mloc, __shfl_xor(mloc, 32));
        float mnew = fmaxf(mrun, mx);
        float scal = vexp2((mrun - mnew) * C1);
        mrun = mnew;
        lrun *= scal;
        oacc0 *= scal;
        oacc1 *= scal;
      }
      float mc = mrun * C1;
#pragma unroll
      for (int r = 0; r < 16; ++r) {
        sc0[r] = vexp2(sc0[r] * C1 - mc);
        sc1[r] = vexp2(sc1[r] * C1 - mc);
      }
      float st[8];
#pragma unroll
      for (int r = 0; r < 8; ++r)
        st[r] = (sc0[2 * r] + sc0[2 * r + 1]) + (sc1[2 * r] + sc1[2 * r + 1]);
      lrun += ((st[0] + st[1]) + (st[2] + st[3])) + ((st[4] + st[5]) + (st[6] + st[7]));

      // ---- P pack -> B-frags via permlane32_swap (T12) ----
      uint32_t pbw[4][4];
#pragma unroll
      for (int s2 = 0; s2 < 4; ++s2) {
        const int s1 = s2 & 1;
#pragma unroll
        for (int p = 0; p < 2; ++p) {
          uint32_t a, b;
          if (s2 < 2) {
            a = cvtpk(sc0[2 * p + 8 * s1], sc0[2 * p + 1 + 8 * s1]);
            b = cvtpk(sc0[2 * p + 4 + 8 * s1], sc0[2 * p + 5 + 8 * s1]);
          } else {
            a = cvtpk(sc1[2 * p + 8 * s1], sc1[2 * p + 1 + 8 * s1]);
            b = cvtpk(sc1[2 * p + 4 + 8 * s1], sc1[2 * p + 5 + 8 * s1]);
          }
          asm volatile("v_permlane32_swap_b32 %0, %1" : "+v"(a), "+v"(b));
          pbw[s2][p] = a;
          pbw[s2][2 + p] = b;
        }
      }

      // ---- PV: O^T += V^T * P, 32x32x16 ----
      __builtin_amdgcn_s_setprio(1);
#pragma unroll
      for (int s2 = 0; s2 < 4; ++s2) {
        bf16x8 bp = pack4(pbw[s2][0], pbw[s2][1], pbw[s2][2], pbw[s2][3]);
        {
          bf16x8 vf = *(const bf16x8*)&bVT[(q31)*64 + (((2 * s2 + g2)) ^ l7) * 8];
          oacc0 = __builtin_amdgcn_mfma_f32_32x32x16_bf16(vf, bp, oacc0, 0, 0, 0);
        }
        {
          bf16x8 vf = *(const bf16x8*)&bVT[(32 + q31) * 64 + (((2 * s2 + g2)) ^ l7) * 8];
          oacc1 = __builtin_amdgcn_mfma_f32_32x32x16_bf16(vf, bp, oacc1, 0, 0, 0);
        }
      }
      __builtin_amdgcn_s_setprio(0);
    }

    __syncthreads();
    cur ^= 1;
  }

  const int b = bh >> 4, h = bh & 15;
  {
    float ls = lrun + __shfl_xor(lrun, 32);
    float inv = 1.0f / ls;
    int tok = qbase + w * 32 + q31;
    size_t rbase = (size_t)(b * S + tok) * D + h * 64;
#pragma unroll
    for (int r2 = 0; r2 < 4; ++r2) {
      uint2 uu;
      uu.x = cvtpk(oacc0[4 * r2] * inv, oacc0[4 * r2 + 1] * inv);
      uu.y = cvtpk(oacc0[4 * r2 + 2] * inv, oacc0[4 * r2 + 3] * inv);
      *(uint2*)&ctx[rbase + 8 * r2 + 4 * g2] = uu;
      uu.x = cvtpk(oacc1[4 * r2] * inv, oacc1[4 * r2 + 1] * inv);
      uu.y = cvtpk(oacc1[4 * r2 + 2] * inv, oacc1[4 * r2 + 3] * inv);
      *(uint2*)&ctx[rbase + 32 + 8 * r2 + 4 * g2] = uu;
    }
  }
}

extern "C" void kernel_launch(void* const* d_in, const int* in_sizes, int n_in,
                              void* d_out, int out_size, void* d_ws, size_t ws_size,
                              hipStream_t stream) {
  const float* x  = (const float*)d_in[0];
  const float* Wq = (const float*)d_in[1];
  const float* Wk = (const float*)d_in[2];
  const float* Wv = (const float*)d_in[3];
  const float* Wo = (const float*)d_in[4];
  const float* bo = (const float*)d_in[5];
  float* out = (float*)d_out;

  if (ws_size < (size_t)120 * 1024 * 1024) return;

  char* ws = (char*)d_ws;
  const size_t MB = 1024 * 1024;
  ushort* xcat = (ushort*)(ws);              // 32MB; ctx aliases (xcat dead after projections)
  ushort* ctx  = (ushort*)(ws);
  ushort* wcat = (ushort*)(ws + 32 * MB);    // 6MB [3072][1024]
  ushort* wob  = (ushort*)(ws + 38 * MB);    // 2MB
  ushort* qhi  = (ushort*)(ws + 40 * MB);    // 16MB each
  ushort* qlo  = (ushort*)(ws + 56 * MB);
  ushort* khi  = (ushort*)(ws + 72 * MB);
  ushort* klo  = (ushort*)(ws + 88 * MB);
  ushort* vt   = (ushort*)(ws + 104 * MB);

  prep_x<<<2048, 256, 0, stream>>>(x, xcat);
  prep_w<<<1024, 256, 0, stream>>>(Wq, Wk, Wv, Wo, wcat, wob);

  // Q,K: 256^2 counted-vmcnt pipeline (grid 32x8 = 256 blocks, 1/CU).
  gemm256<<<dim3(32, 8), 512, 0, stream>>>(xcat, wcat, qhi, qlo, khi, klo);
  // V: 128^2 counted-vmcnt pipeline (K=1024 hi-only via stride 2048).
  gemm128p<1, 1024, 1024, 2048><<<dim3(64, 8), 256, 0, stream>>>(
      xcat, wcat + 2 * D * D, vt, nullptr, nullptr);

  flash16<<<dim3(BATCH * H, S / 128), 256, 0, stream>>>(qhi, qlo, khi, klo, vt, ctx);

  // out-projection: 128^2 counted-vmcnt pipeline.
  gemm128p<2, 1024, 1024, 1024><<<dim3(64, 8), 256, 0, stream>>>(
      ctx, wob, nullptr, out, bo);
}

// Round 19
// 320.445 us; speedup vs baseline: 1.1171x; 1.0234x over previous
//
#include <hip/hip_runtime.h>
#include <hip/hip_bf16.h>
#include <cstdint>
#include <cstddef>

#define S 4096
#define D 1024
#define H 16
#define HD 64
#define BATCH 2
#define M_TOK 8192   // BATCH*S
#define K2 2048

typedef short short8 __attribute__((ext_vector_type(8)));
typedef __bf16 bf16x8 __attribute__((ext_vector_type(8)));
typedef float f32x4 __attribute__((ext_vector_type(4)));
typedef float f32x16 __attribute__((ext_vector_type(16)));
typedef unsigned int u32;

static __device__ __forceinline__ ushort f2bf(float f) {
  union { float f; uint32_t u; } v; v.f = f;
  uint32_t u = v.u + 0x7FFFu + ((v.u >> 16) & 1u);
  return (ushort)(u >> 16);
}
static __device__ __forceinline__ float bf2f(ushort h) {
  union { uint32_t u; float f; } v; v.u = ((uint32_t)h) << 16; return v.f;
}
static __device__ __forceinline__ uint32_t cvtpk(float lo, float hi) {
  uint32_t r;
  asm("v_cvt_pk_bf16_f32 %0, %1, %2" : "=v"(r) : "v"(lo), "v"(hi));
  return r;
}
static __device__ __forceinline__ float vexp2(float x) {
  float r;
  asm("v_exp_f32 %0, %1" : "=v"(r) : "v"(x));
  return r;
}
static __device__ __forceinline__ bf16x8 pack4(uint32_t a, uint32_t b, uint32_t c, uint32_t d) {
  union { uint32_t u[4]; bf16x8 v; } z;
  z.u[0] = a; z.u[1] = b; z.u[2] = c; z.u[3] = d;
  return z.v;
}
// async global->LDS, 16B per lane; LDS dest = wave-uniform base + lane*16
static __device__ __forceinline__ void gld16(const void* g, void* l) {
  __builtin_amdgcn_global_load_lds(
      (const __attribute__((address_space(1))) u32*)g,
      (__attribute__((address_space(3))) u32*)l, 16, 0, 0);
}
static __device__ __forceinline__ ushort sgn(float a) {
  return a > 0.f ? 0x3F80 : (a < 0.f ? 0xBF80 : 0);
}

// ---------------- fused prep: blocks [0,2048) do x -> hi|lo; blocks [2048,2304) do W signs ----------------
__global__ void prep_all(const float* __restrict__ x, ushort* __restrict__ xcat,
                         const float* __restrict__ wq, const float* __restrict__ wk,
                         const float* __restrict__ wv, const float* __restrict__ wo,
                         ushort* __restrict__ wcat, ushort* __restrict__ wob) {
  if (blockIdx.x < 2048) {
    int i = blockIdx.x * blockDim.x + threadIdx.x;
    const int total = M_TOK * 128;   // groups of 8 floats
    for (; i < total; i += 2048 * blockDim.x) {
      int row = i >> 7, c8 = (i & 127) * 8;
      const float* px = &x[(size_t)row * 1024 + c8];
      float4 a = *(const float4*)px;
      float4 b = *(const float4*)(px + 4);
      float va[8] = {a.x, a.y, a.z, a.w, b.x, b.y, b.z, b.w};
      union { ushort u[8]; short8 v; } Hh, Ll;
#pragma unroll
      for (int j = 0; j < 8; ++j) {
        ushort h = f2bf(va[j]);
        Hh.u[j] = h;
        Ll.u[j] = f2bf(va[j] - bf2f(h));
      }
      *(short8*)&xcat[(size_t)row * K2 + c8] = Hh.v;
      *(short8*)&xcat[(size_t)row * K2 + 1024 + c8] = Ll.v;
    }
  } else {
    int i = (blockIdx.x - 2048) * blockDim.x + threadIdx.x;
    const int total = (D * D) / 4;
    for (; i < total; i += 256 * blockDim.x) {
      float4 a;
      union { ushort u[4]; uint2 v; } t;
      a = *(const float4*)&wq[i * 4];
      t.u[0] = sgn(a.x); t.u[1] = sgn(a.y); t.u[2] = sgn(a.z); t.u[3] = sgn(a.w);
      *(uint2*)&wcat[i * 4] = t.v;
      a = *(const float4*)&wk[i * 4];
      t.u[0] = sgn(a.x); t.u[1] = sgn(a.y); t.u[2] = sgn(a.z); t.u[3] = sgn(a.w);
      *(uint2*)&wcat[D * D + i * 4] = t.v;
      a = *(const float4*)&wv[i * 4];
      t.u[0] = sgn(a.x); t.u[1] = sgn(a.y); t.u[2] = sgn(a.z); t.u[3] = sgn(a.w);
      *(uint2*)&wcat[2 * D * D + i * 4] = t.v;
      a = *(const float4*)&wo[i * 4];
      t.u[0] = sgn(a.x); t.u[1] = sgn(a.y); t.u[2] = sgn(a.z); t.u[3] = sgn(a.w);
      *(uint2*)&wob[i * 4] = t.v;
    }
  }
}

// ---------------- gemm256: 256x256 tile, BK=32, 3-buffer counted-vmcnt pipeline (T3+T4) ----------------
// Q/K only (grid 32x8): K=2048 over hi|lo (B rows wrap at 1024), hi-lo epilogue.
__global__ __launch_bounds__(512, 2) void gemm256(
    const ushort* __restrict__ A, const ushort* __restrict__ Bw,
    ushort* __restrict__ q_hi, ushort* __restrict__ q_lo,
    ushort* __restrict__ k_hi, ushort* __restrict__ k_lo)
{
  __shared__ ushort smA[3][256 * 32];
  __shared__ ushort smB[3][256 * 32];
  const int tid = threadIdx.x;
  const int l = tid & 63;
  const int w = tid >> 6;          // 0..7
  const int x = l & 15, g = l >> 4;
  const int wm = w >> 2, wn = w & 3;
  const int bm = blockIdx.x, bn = blockIdx.y;

  const ushort* gA[2]; const ushort* gB[2]; int ldso[2];
#pragma unroll
  for (int r = 0; r < 2; ++r) {
    int q = r * 512 + tid;
    int row = q >> 2;
    int blk = (q & 3) ^ ((row & 3) ^ ((row >> 2) & 3));
    gA[r] = &A[(size_t)(bm * 256 + row) * 2048 + blk * 8];
    gB[r] = &Bw[(size_t)(bn * 256 + row) * 1024 + blk * 8];
    ldso[r] = (r * 512 + w * 64) * 8;
  }

  f32x4 acc[8][4] = {};

#pragma unroll
  for (int r = 0; r < 2; ++r) {
    gld16(gA[r] + 0, &smA[0][ldso[r]]);
    gld16(gB[r] + 0, &smB[0][ldso[r]]);
  }
#pragma unroll
  for (int r = 0; r < 2; ++r) {
    gld16(gA[r] + 32, &smA[1][ldso[r]]);
    gld16(gB[r] + ((32) & 1023), &smB[1][ldso[r]]);
  }

  const int swz = (x & 3) ^ ((x >> 2) & 3);
  int cb = 0;
  for (int s = 0; s < 64; ++s) {
    if (s < 63) {
      asm volatile("s_waitcnt vmcnt(4)" ::: "memory");
    } else {
      asm volatile("s_waitcnt vmcnt(0)" ::: "memory");
    }
    __builtin_amdgcn_s_barrier();

    if (s + 2 < 64) {
      int nb = cb - 1; if (nb < 0) nb = 2;
      int k0 = (s + 2) * 32;
#pragma unroll
      for (int r = 0; r < 2; ++r) {
        gld16(gA[r] + k0, &smA[nb][ldso[r]]);
        gld16(gB[r] + (k0 & 1023), &smB[nb][ldso[r]]);
      }
    }

    const ushort* bA = smA[cb];
    const ushort* bB = smB[cb];
    bf16x8 af[8], bf_[4];
#pragma unroll
    for (int m = 0; m < 8; ++m)
      af[m] = *(const bf16x8*)&bA[(wm * 128 + m * 16 + x) * 32 + (g ^ swz) * 8];
#pragma unroll
    for (int n = 0; n < 4; ++n)
      bf_[n] = *(const bf16x8*)&bB[(wn * 64 + n * 16 + x) * 32 + (g ^ swz) * 8];

    __builtin_amdgcn_s_setprio(1);
#pragma unroll
    for (int m = 0; m < 8; ++m)
#pragma unroll
      for (int n = 0; n < 4; ++n)
        acc[m][n] = __builtin_amdgcn_mfma_f32_16x16x32_bf16(af[m], bf_[n], acc[m][n], 0, 0, 0);
    __builtin_amdgcn_s_setprio(0);

    cb = (cb == 2) ? 0 : cb + 1;
  }

#pragma unroll
  for (int m = 0; m < 8; ++m)
#pragma unroll
    for (int n = 0; n < 4; ++n)
#pragma unroll
      for (int r = 0; r < 4; ++r) {
        int rowg = bm * 256 + wm * 128 + m * 16 + g * 4 + r;
        int colg = bn * 256 + wn * 64 + n * 16 + x;
        float v = acc[m][n][r];
        int bi = rowg >> 12, ntok = rowg & 4095;
        int proj = colg >> 10;
        int cg = colg & 1023;
        int h = cg >> 6, hd = cg & 63;
        ushort* oh = (proj == 0) ? q_hi : k_hi;
        ushort* ol = (proj == 0) ? q_lo : k_lo;
        size_t off = (size_t)(bi * H + h) * (S * HD) + (size_t)ntok * HD + hd;
        ushort hiv = f2bf(v);
        oh[off] = hiv;
        ol[off] = f2bf(v - bf2f(hiv));
      }
}

// ---------------- GEMM (m97): EPI 1: plain V^T epilogue. EPI 2: fp32 + bias. ----------------
template<int EPI, int KK, int BROW, int AST>
__global__ __launch_bounds__(256) void gemm97(
    const ushort* __restrict__ A, const ushort* __restrict__ Bw,
    ushort* __restrict__ v_t,
    float* __restrict__ of, const float* __restrict__ bias)
{
  __shared__ ushort smA[128 * 32];
  __shared__ ushort smB[128 * 32];
  const int tid = threadIdx.x;
  const int l = tid & 63;
  const int w = tid >> 6;
  const int x = l & 15, g = l >> 4;
  const int wm = w >> 1, wn = w & 1;
  const int bm = blockIdx.x, bn = blockIdx.y;

  const ushort* gA[2]; const ushort* gB[2]; int ldso[2];
#pragma unroll
  for (int p = 0; p < 2; ++p) {
    int q = p * 256 + tid;
    gA[p] = &A[(size_t)(bm * 128 + (q >> 2)) * AST + (q & 3) * 8];
    gB[p] = &Bw[(size_t)(bn * 128 + (q >> 2)) * BROW + (q & 3) * 8];
    ldso[p] = (p * 256 + w * 64) * 8;
  }

  f32x4 acc[4][4] = {};

  for (int k0 = 0; k0 < KK; k0 += 32) {
    __syncthreads();
#pragma unroll
    for (int p = 0; p < 2; ++p) {
      gld16(gA[p] + k0, &smA[ldso[p]]);
      gld16(gB[p] + (k0 & (BROW - 1)), &smB[ldso[p]]);
    }
    __syncthreads();
    bf16x8 af[4], bf_[4];
#pragma unroll
    for (int m = 0; m < 4; ++m)
      af[m] = *(const bf16x8*)&smA[(wm * 64 + m * 16 + x) * 32 + g * 8];
#pragma unroll
    for (int n = 0; n < 4; ++n)
      bf_[n] = *(const bf16x8*)&smB[(wn * 64 + n * 16 + x) * 32 + g * 8];
#pragma unroll
    for (int m = 0; m < 4; ++m)
#pragma unroll
      for (int n = 0; n < 4; ++n)
        acc[m][n] = __builtin_amdgcn_mfma_f32_16x16x32_bf16(af[m], bf_[n], acc[m][n], 0, 0, 0);
  }

#pragma unroll
  for (int m = 0; m < 4; ++m)
#pragma unroll
    for (int n = 0; n < 4; ++n)
#pragma unroll
      for (int r = 0; r < 4; ++r) {
        int rowg = bm * 128 + wm * 64 + m * 16 + g * 4 + r;
        int colg = bn * 128 + wn * 64 + n * 16 + x;
        float v = acc[m][n][r];
        if (EPI == 2) {
          of[(size_t)rowg * D + colg] = v + bias[colg];
        } else {
          int bi = rowg >> 12, ntok = rowg & 4095;
          int cg = colg & 1023;
          int h = cg >> 6, hd = cg & 63;
          size_t bhb = (size_t)(bi * H + h) * (S * HD);
          v_t[bhb + (size_t)hd * S + ntok] = f2bf(v);   // plain V^T
        }
      }
}

// ---------------- flash16: 32x32x16 MFMA (best flash: 195us), T12 permlane P-pack ----------------
__global__ __launch_bounds__(256) void flash16(
    const ushort* __restrict__ qhi, const ushort* __restrict__ qlo,
    const ushort* __restrict__ khi, const ushort* __restrict__ klo,
    const ushort* __restrict__ vt, ushort* __restrict__ ctx)
{
  __shared__ ushort smKhi[2][64 * 64];
  __shared__ ushort smKlo[2][64 * 64];
  __shared__ ushort smVT[2][64 * 64];

  const int tid = threadIdx.x;
  const int l = tid & 63;
  const int w = tid >> 6;
  const int q31 = l & 31;
  const int g2 = l >> 5;        // 0..1
  const int l7 = l & 7;
  const int bh = blockIdx.x;
  const int qt = (int)(gridDim.y - 1) - (int)blockIdx.y;   // heavy tiles first
  const int qbase = qt * 128;
  const size_t qkbase = (size_t)bh * S * HD;

  int soff_k[2]; size_t soff_v[2]; int ldso[2];
#pragma unroll
  for (int p = 0; p < 2; ++p) {
    int q = p * 256 + tid;
    int r2 = q >> 3;
    int sb = (q & 7) ^ (r2 & 7);
    soff_k[p] = r2 * HD + sb * 8;
    soff_v[p] = (size_t)r2 * S + sb * 8;
    ldso[p] = (p * 256 + w * 64) * 8;
  }
  const ushort* khb = khi + qkbase;
  const ushort* klb = klo + qkbase;
  const ushort* vtb = vt + qkbase;

  // Q fragments (B-operand of 32x32x16): [hi/lo][s2]; lane: q=q31, d = 16*s2 + 8*g2 + j
  bf16x8 bq[2][4];
  {
    int qrow = qbase + w * 32 + q31;
    size_t base = qkbase + (size_t)qrow * HD + g2 * 8;
#pragma unroll
    for (int s2 = 0; s2 < 4; ++s2) {
      bq[0][s2] = *(const bf16x8*)&qhi[base + s2 * 16];
      bq[1][s2] = *(const bf16x8*)&qlo[base + s2 * 16];
    }
  }

  float mrun = -1e30f;
  float lrun = 0.f;            // lane-partial; reduced at epilogue
  f32x16 oacc0 = {}, oacc1 = {};

  const int kvmax = (qbase + 127) >> 6;
  const int qmaxw = qbase + w * 32 + 31;
  const float C1 = 0.125f * 1.44269504f;
  const float TH = 8.0f / C1;

#pragma unroll
  for (int p = 0; p < 2; ++p) {
    gld16(khb + soff_k[p], &smKhi[0][ldso[p]]);
    gld16(klb + soff_k[p], &smKlo[0][ldso[p]]);
    gld16(vtb + soff_v[p], &smVT[0][ldso[p]]);
  }
  __syncthreads();

  int cur = 0;
  for (int kv = 0; kv <= kvmax; ++kv) {
    if (kv < kvmax) {
      const ushort* kh = khb + (size_t)(kv + 1) * (64 * HD);
      const ushort* kl = klb + (size_t)(kv + 1) * (64 * HD);
      const ushort* vp = vtb + (size_t)(kv + 1) * 64;
      int nb = cur ^ 1;
#pragma unroll
      for (int p = 0; p < 2; ++p) {
        gld16(kh + soff_k[p], &smKhi[nb][ldso[p]]);
        gld16(kl + soff_k[p], &smKlo[nb][ldso[p]]);
        gld16(vp + soff_v[p], &smVT[nb][ldso[p]]);
      }
    }

    if (kv * 64 <= qmaxw) {
      const ushort* bKhi = smKhi[cur];
      const ushort* bKlo = smKlo[cur];
      const ushort* bVT = smVT[cur];

      // ---- QK^T swapped, 32x32x16: sc[T] covers k-tokens [32T, 32T+32) x 32 q ----
      f32x16 sc0 = {}, sc1 = {};
      __builtin_amdgcn_s_setprio(1);
#pragma unroll
      for (int s2 = 0; s2 < 4; ++s2) {
        {
          int pb = q31 * 64 + (((2 * s2 + g2)) ^ l7) * 8;
          bf16x8 kH = *(const bf16x8*)&bKhi[pb];
          bf16x8 kL = *(const bf16x8*)&bKlo[pb];
          sc0 = __builtin_amdgcn_mfma_f32_32x32x16_bf16(kH, bq[0][s2], sc0, 0, 0, 0);
          sc0 = __builtin_amdgcn_mfma_f32_32x32x16_bf16(kL, bq[0][s2], sc0, 0, 0, 0);
          sc0 = __builtin_amdgcn_mfma_f32_32x32x16_bf16(kH, bq[1][s2], sc0, 0, 0, 0);
        }
        {
          int pb = (32 + q31) * 64 + (((2 * s2 + g2)) ^ l7) * 8;
          bf16x8 kH = *(const bf16x8*)&bKhi[pb];
          bf16x8 kL = *(const bf16x8*)&bKlo[pb];
          sc1 = __builtin_amdgcn_mfma_f32_32x32x16_bf16(kH, bq[0][s2], sc1, 0, 0, 0);
          sc1 = __builtin_amdgcn_mfma_f32_32x32x16_bf16(kL, bq[0][s2], sc1, 0, 0, 0);
          sc1 = __builtin_amdgcn_mfma_f32_32x32x16_bf16(kH, bq[1][s2], sc1, 0, 0, 0);
        }
      }
      __builtin_amdgcn_s_setprio(0);

      // ---- mask (diagonal tiles only) ----
      if (kv * 64 + 63 > qbase + w * 32) {
        int qglob = qbase + w * 32 + q31;
        int kb = kv * 64 + 4 * g2;
#pragma unroll
        for (int r = 0; r < 16; ++r) {
          int k5 = (r & 3) + 8 * (r >> 2);
          if (kb + k5 > qglob) sc0[r] = -1e30f;
          if (kb + 32 + k5 > qglob) sc1[r] = -1e30f;
        }
      }

      // ---- softmax (lane-local 32) ----
      float mt[8];
#pragma unroll
      for (int r = 0; r < 8; ++r)
        mt[r] = fmaxf(fmaxf(sc0[2 * r], sc0[2 * r + 1]), fmaxf(sc1[2 * r], sc1[2 * r + 1]));
      float mloc = fmaxf(fmaxf(fmaxf(mt[0], mt[1]), fmaxf(mt[2], mt[3])),
                         fmaxf(fmaxf(mt[4], mt[5]), fmaxf(mt[6], mt[7])));
      if (__any(mloc > mrun + TH)) {
        float mx = fmaxf(mloc, __shfl_xor(mloc, 32));
        float mnew = fmaxf(mrun, mx);
        float scal = vexp2((mrun - mnew) * C1);
        mrun = mnew;
        lrun *= scal;
        oacc0 *= scal;
        oacc1 *= scal;
      }
      float mc = mrun * C1;
#pragma unroll
      for (int r = 0; r < 16; ++r) {
        sc0[r] = vexp2(sc0[r] * C1 - mc);
        sc1[r] = vexp2(sc1[r] * C1 - mc);
      }
      float st[8];
#pragma unroll
      for (int r = 0; r < 8; ++r)
        st[r] = (sc0[2 * r] + sc0[2 * r + 1]) + (sc1[2 * r] + sc1[2 * r + 1]);
      lrun += ((st[0] + st[1]) + (st[2] + st[3])) + ((st[4] + st[5]) + (st[6] + st[7]));

      // ---- P pack -> B-frags via permlane32_swap (T12) ----
      uint32_t pbw[4][4];
#pragma unroll
      for (int s2 = 0; s2 < 4; ++s2) {
        const int s1 = s2 & 1;
#pragma unroll
        for (int p = 0; p < 2; ++p) {
          uint32_t a, b;
          if (s2 < 2) {
            a = cvtpk(sc0[2 * p + 8 * s1], sc0[2 * p + 1 + 8 * s1]);
            b = cvtpk(sc0[2 * p + 4 + 8 * s1], sc0[2 * p + 5 + 8 * s1]);
          } else {
            a = cvtpk(sc1[2 * p + 8 * s1], sc1[2 * p + 1 + 8 * s1]);
            b = cvtpk(sc1[2 * p + 4 + 8 * s1], sc1[2 * p + 5 + 8 * s1]);
          }
          asm volatile("v_permlane32_swap_b32 %0, %1" : "+v"(a), "+v"(b));
          pbw[s2][p] = a;
          pbw[s2][2 + p] = b;
        }
      }

      // ---- PV: O^T += V^T * P, 32x32x16 ----
      __builtin_amdgcn_s_setprio(1);
#pragma unroll
      for (int s2 = 0; s2 < 4; ++s2) {
        bf16x8 bp = pack4(pbw[s2][0], pbw[s2][1], pbw[s2][2], pbw[s2][3]);
        {
          bf16x8 vf = *(const bf16x8*)&bVT[(q31)*64 + (((2 * s2 + g2)) ^ l7) * 8];
          oacc0 = __builtin_amdgcn_mfma_f32_32x32x16_bf16(vf, bp, oacc0, 0, 0, 0);
        }
        {
          bf16x8 vf = *(const bf16x8*)&bVT[(32 + q31) * 64 + (((2 * s2 + g2)) ^ l7) * 8];
          oacc1 = __builtin_amdgcn_mfma_f32_32x32x16_bf16(vf, bp, oacc1, 0, 0, 0);
        }
      }
      __builtin_amdgcn_s_setprio(0);
    }

    __syncthreads();
    cur ^= 1;
  }

  const int b = bh >> 4, h = bh & 15;
  {
    float ls = lrun + __shfl_xor(lrun, 32);
    float inv = 1.0f / ls;
    int tok = qbase + w * 32 + q31;
    size_t rbase = (size_t)(b * S + tok) * D + h * 64;
#pragma unroll
    for (int r2 = 0; r2 < 4; ++r2) {
      uint2 uu;
      uu.x = cvtpk(oacc0[4 * r2] * inv, oacc0[4 * r2 + 1] * inv);
      uu.y = cvtpk(oacc0[4 * r2 + 2] * inv, oacc0[4 * r2 + 3] * inv);
      *(uint2*)&ctx[rbase + 8 * r2 + 4 * g2] = uu;
      uu.x = cvtpk(oacc1[4 * r2] * inv, oacc1[4 * r2 + 1] * inv);
      uu.y = cvtpk(oacc1[4 * r2 + 2] * inv, oacc1[4 * r2 + 3] * inv);
      *(uint2*)&ctx[rbase + 32 + 8 * r2 + 4 * g2] = uu;
    }
  }
}

extern "C" void kernel_launch(void* const* d_in, const int* in_sizes, int n_in,
                              void* d_out, int out_size, void* d_ws, size_t ws_size,
                              hipStream_t stream) {
  const float* x  = (const float*)d_in[0];
  const float* Wq = (const float*)d_in[1];
  const float* Wk = (const float*)d_in[2];
  const float* Wv = (const float*)d_in[3];
  const float* Wo = (const float*)d_in[4];
  const float* bo = (const float*)d_in[5];
  float* out = (float*)d_out;

  if (ws_size < (size_t)120 * 1024 * 1024) return;

  char* ws = (char*)d_ws;
  const size_t MB = 1024 * 1024;
  ushort* xcat = (ushort*)(ws);              // 32MB; ctx aliases (xcat dead after projections)
  ushort* ctx  = (ushort*)(ws);
  ushort* wcat = (ushort*)(ws + 32 * MB);    // 6MB [3072][1024]
  ushort* wob  = (ushort*)(ws + 38 * MB);    // 2MB
  ushort* qhi  = (ushort*)(ws + 40 * MB);    // 16MB each
  ushort* qlo  = (ushort*)(ws + 56 * MB);
  ushort* khi  = (ushort*)(ws + 72 * MB);
  ushort* klo  = (ushort*)(ws + 88 * MB);
  ushort* vt   = (ushort*)(ws + 104 * MB);

  prep_all<<<2304, 256, 0, stream>>>(x, xcat, Wq, Wk, Wv, Wo, wcat, wob);

  // Q,K: 256^2 counted-vmcnt pipeline.
  gemm256<<<dim3(32, 8), 512, 0, stream>>>(xcat, wcat, qhi, qlo, khi, klo);
  // V: 128^2 m97 structure (K=1024 hi-only via stride 2048) — R15-proven config.
  gemm97<1, 1024, 1024, 2048><<<dim3(64, 8), 256, 0, stream>>>(
      xcat, wcat + 2 * D * D, vt, nullptr, nullptr);

  flash16<<<dim3(BATCH * H, S / 128), 256, 0, stream>>>(qhi, qlo, khi, klo, vt, ctx);

  // out-projection: 128^2 m97 structure.
  gemm97<2, 1024, 1024, 1024><<<dim3(64, 8), 256, 0, stream>>>(
      ctx, wob, nullptr, out, bo);
}